// Round 14
// baseline (238.965 us; speedup 1.0000x reference)
//
#include <hip/hip_runtime.h>
#include <hip/hip_fp16.h>
#include <cstddef>
#include <cstdint>

#define C 128

typedef short bf16x8 __attribute__((ext_vector_type(8)));
typedef float f32x4 __attribute__((ext_vector_type(4)));

__device__ __forceinline__ unsigned f2bf_hi(float f) {
  unsigned u = __float_as_uint(f);
  return (u + 0x7fffu + ((u >> 16) & 1u)) >> 16;
}

__device__ __forceinline__ float4 gather8B(const __half* p) {
  const uint2 u = *reinterpret_cast<const uint2*>(p);
  const __half2 a = *reinterpret_cast<const __half2*>(&u.x);
  const __half2 b = *reinterpret_cast<const __half2*>(&u.y);
  const float2 lo = __half22float2(a), hi = __half22float2(b);
  return make_float4(lo.x, lo.y, hi.x, hi.y);
}

__device__ __forceinline__ void fma4(float4& acc, float v, const float4& g) {
  acc.x += v * g.x; acc.y += v * g.y; acc.z += v * g.z; acc.w += v * g.w;
}

__device__ __forceinline__ void red4(float4& a) {
  a.x += __shfl_xor(a.x, 32);
  a.y += __shfl_xor(a.y, 32);
  a.z += __shfl_xor(a.z, 32);
  a.w += __shfl_xor(a.w, 32);
}

// ---- fused prep: W planes + x hi/lo split + cursor zeroing ------------
// W layout (verified R8): 12 planes (j*4 + half*2 + ch), 8192 shorts each;
// off = kc*2048 + ct*512 + (g*16+l15)*8 + i.
__global__ __launch_bounds__(256) void prep_fused(
    const float* __restrict__ W, unsigned short* __restrict__ wf,
    const float* __restrict__ x, unsigned short* __restrict__ xh,
    unsigned short* __restrict__ xl, int* __restrict__ cursor,
    int N, int NP) {
  const int idx = blockIdx.x * 256 + threadIdx.x;
  if (idx < NP * C) {
    const float v = (idx < N * C) ? x[idx] : 0.0f;
    const unsigned hb = f2bf_hi(v);
    const unsigned lb = f2bf_hi(v - __uint_as_float(hb << 16));
    xh[idx] = (unsigned short)hb;
    xl[idx] = (unsigned short)lb;
  }
  if (idx < 3 * 128 * 128) {
    const int j = idx >> 14, k = (idx >> 7) & 127, c = idx & 127;
    const float v = W[idx];
    const unsigned hb = f2bf_hi(v);
    const unsigned lb = f2bf_hi(v - __uint_as_float(hb << 16));
    const int ch = c >> 6, cc = c & 63, ct = cc >> 4, l15 = cc & 15;
    const int kc = k >> 5, kk = k & 31, g = kk >> 3, i = kk & 7;
    const int off = kc * 2048 + ct * 512 + (g * 16 + l15) * 8 + i;
    wf[(size_t)(j * 4 + 0 + ch) * 8192 + off] = (unsigned short)hb;
    wf[(size_t)(j * 4 + 2 + ch) * 8192 + off] = (unsigned short)lb;
  }
  if (idx < N) cursor[idx] = 0;
}

// ---- fused 3x linear: W-stationary in VGPRs, stream x rows ------------
// chunk = 128 rows (8 tiles of 16; 2 tiles per wave). grid = 6 * NP/128.
// bid -> (chunk, v): chunk = (bid%8) + 8*(bid/48), v = (bid%48)>>3 = j*2+ch.
// launch_bounds (256,4): 4 blocks/CU resident (VGPR<=128) for latency hiding.
__global__ __launch_bounds__(256, 4) void gemm3_ws(
    const unsigned short* __restrict__ xh, const unsigned short* __restrict__ xl,
    const unsigned short* __restrict__ wf, const float* __restrict__ bias,
    float* __restrict__ out, __half* __restrict__ h12, int N) {
  const int bid = blockIdx.x;
  const int q48 = bid / 48, r48 = bid % 48;
  const int chunk = (r48 & 7) + 8 * q48;
  const int v = r48 >> 3;  // 0..5
  const int j = v >> 1, ch = v & 1;
  const int tid = threadIdx.x;
  const int lane = tid & 63, wid = tid >> 6;
  const int l15 = lane & 15, g = lane >> 4;

  // stationary B fragments (128 VGPRs)
  const unsigned short* ph = wf + (size_t)(j * 4 + 0 + ch) * 8192 + lane * 8;
  const unsigned short* pl = wf + (size_t)(j * 4 + 2 + ch) * 8192 + lane * 8;
  bf16x8 bh[4][4], bl[4][4];
#pragma unroll
  for (int kc = 0; kc < 4; ++kc)
#pragma unroll
    for (int ct = 0; ct < 4; ++ct) {
      bh[kc][ct] = *reinterpret_cast<const bf16x8*>(ph + kc * 2048 + ct * 512);
      bl[kc][ct] = *reinterpret_cast<const bf16x8*>(pl + kc * 2048 + ct * 512);
    }

  float bv[4];
#pragma unroll
  for (int ct = 0; ct < 4; ++ct) bv[ct] = bias[j * C + ch * 64 + ct * 16 + l15];

  const int t0 = chunk * 8 + wid;  // 2 tiles per wave: t0, t0+4

  bf16x8 a0h[4], a0l[4], a1h[4], a1l[4];

#define LOADA(AH, AL, T)                                                    \
  {                                                                         \
    const size_t ar = (size_t)((T)*16 + l15) * C + g * 8;                   \
    _Pragma("unroll") for (int kc = 0; kc < 4; ++kc) {                      \
      AH[kc] = *reinterpret_cast<const bf16x8*>(xh + ar + kc * 32);         \
      AL[kc] = *reinterpret_cast<const bf16x8*>(xl + ar + kc * 32);         \
    }                                                                       \
  }

#define COMPSTORE(AH, AL, T)                                                \
  {                                                                         \
    f32x4 acc[4];                                                           \
    _Pragma("unroll") for (int ct = 0; ct < 4; ++ct)                        \
        acc[ct] = (f32x4){0.f, 0.f, 0.f, 0.f};                              \
    _Pragma("unroll") for (int kc = 0; kc < 4; ++kc)                        \
        _Pragma("unroll") for (int ct = 0; ct < 4; ++ct) {                  \
      acc[ct] = __builtin_amdgcn_mfma_f32_16x16x32_bf16(AH[kc], bh[kc][ct], \
                                                        acc[ct], 0, 0, 0);  \
      acc[ct] = __builtin_amdgcn_mfma_f32_16x16x32_bf16(AL[kc], bh[kc][ct], \
                                                        acc[ct], 0, 0, 0);  \
      acc[ct] = __builtin_amdgcn_mfma_f32_16x16x32_bf16(AH[kc], bl[kc][ct], \
                                                        acc[ct], 0, 0, 0);  \
    }                                                                       \
    const int grb = (T)*16 + g * 4;                                         \
    if (j == 0) {                                                           \
      _Pragma("unroll") for (int ct = 0; ct < 4; ++ct) {                    \
        const int col = ch * 64 + ct * 16 + l15;                            \
        _Pragma("unroll") for (int qq = 0; qq < 4; ++qq) {                  \
          const int gr = grb + qq;                                          \
          if (gr < N) out[(size_t)gr * 384 + col] = acc[ct][qq] + bv[ct];   \
        }                                                                   \
      }                                                                     \
    } else {                                                                \
      __half* const hp = h12 + ((j == 2) ? 128 : 0);                        \
      _Pragma("unroll") for (int ct = 0; ct < 4; ++ct) {                    \
        const int colb = ch * 64 + ct * 16 + (l15 & ~1);                    \
        _Pragma("unroll") for (int qq = 0; qq < 4; ++qq) {                  \
          const int gr = grb + qq;                                          \
          const float fv = acc[ct][qq] + bv[ct];                            \
          const unsigned mine = (unsigned)__half_as_ushort(__float2half(fv));\
          const unsigned nbr = (unsigned)__shfl_xor((int)mine, 1);          \
          if (((l15 & 1) == 0) && gr < N) {                                 \
            *reinterpret_cast<unsigned*>(hp + (size_t)gr * 256 + colb) =    \
                mine | (nbr << 16);                                         \
          }                                                                 \
        }                                                                   \
      }                                                                     \
    }                                                                       \
  }

  // both tiles' A-frags loaded up-front (16 loads in flight)
  LOADA(a0h, a0l, t0);
  LOADA(a1h, a1l, t0 + 4);
  COMPSTORE(a0h, a0l, t0);
  COMPSTORE(a1h, a1l, t0 + 4);
#undef LOADA
#undef COMPSTORE
}

// ---- CSR build --------------------------------------------------------
__global__ __launch_bounds__(256) void hist_rows(
    const int* __restrict__ row, int* __restrict__ cnt, int E) {
  int i = blockIdx.x * 256 + threadIdx.x;
  int stride = gridDim.x * 256;
  for (; i < E; i += stride) atomicAdd(&cnt[row[i]], 1);
}

__global__ __launch_bounds__(1024) void scan_local(
    const int* __restrict__ cnt, int* __restrict__ part,
    int* __restrict__ bsum, int N) {
  __shared__ int wsum[16];
  const int tid = threadIdx.x;
  const int i = blockIdx.x * 1024 + tid;
  const int v = (i < N) ? cnt[i] : 0;
  const int lane = tid & 63, w = tid >> 6;
  int s = v;
#pragma unroll
  for (int off = 1; off < 64; off <<= 1) {
    int t = __shfl_up(s, off, 64);
    if (lane >= off) s += t;
  }
  if (lane == 63) wsum[w] = s;
  __syncthreads();
  if (tid < 16) {
    int ws = wsum[tid];
#pragma unroll
    for (int off = 1; off < 16; off <<= 1) {
      int t = __shfl_up(ws, off, 16);
      if (tid >= off) ws += t;
    }
    wsum[tid] = ws;
  }
  __syncthreads();
  const int woff = w ? wsum[w - 1] : 0;
  if (i < N) part[i] = woff + s - v;
  if (tid == 0) bsum[blockIdx.x] = wsum[15];
}

// apply: part[i] += carry(bid); cursor = part; block0 writes row_ptr[N].
__global__ __launch_bounds__(1024) void scan_apply2(
    int* __restrict__ part, const int* __restrict__ bsum,
    int* __restrict__ cursor, int* __restrict__ row_ptr, int nb, int N) {
  __shared__ int carry_s;
  const int tid = threadIdx.x;
  if (tid < 64) {
    const int v = (tid < nb) ? bsum[tid] : 0;
    int s = v;
#pragma unroll
    for (int off = 1; off < 64; off <<= 1) {
      int t = __shfl_up(s, off, 64);
      if (tid >= off) s += t;
    }
    if (tid == (int)blockIdx.x) carry_s = s - v;
    if (blockIdx.x == 0 && tid == 63) row_ptr[N] = s;
  }
  __syncthreads();
  const int i = blockIdx.x * 1024 + tid;
  if (i < N) {
    const int v = part[i] + carry_s;
    part[i] = v;
    cursor[i] = v;
  }
}

__global__ __launch_bounds__(256) void scatter_edges(
    const int* __restrict__ row, const int* __restrict__ col,
    const float* __restrict__ val, int* __restrict__ cursor,
    int2* __restrict__ ep, int E) {
  int i = blockIdx.x * 256 + threadIdx.x;
  int stride = gridDim.x * 256;
  for (; i < E; i += stride) {
    int r = row[i];
    int pos = atomicAdd(&cursor[r], 1);
    ep[pos] = make_int2(col[i], __float_as_int(val[i]));
  }
}

// ---- SpMM merged: out[:,128:256] = A h1 ; t = A h2 --------------------
__global__ __launch_bounds__(256) void spmm12(
    const __half* __restrict__ h12, const int* __restrict__ rp,
    const int2* __restrict__ ep, float* __restrict__ out,
    __half* __restrict__ t, int tstride, int N) {
  const int r = blockIdx.x * 4 + (threadIdx.x >> 6);
  if (r >= N) return;
  const int lane = threadIdx.x & 63;
  const int half = lane >> 5;
  const int c4 = (lane & 31) << 2;
  const int s = rp[r], e = rp[r + 1];
  float4 p0 = make_float4(0.f, 0.f, 0.f, 0.f), p1 = p0, q0 = p0, q1 = p0;
  int i = s + half;
  for (; i + 2 < e; i += 4) {
    const int2 e0 = ep[i], e1 = ep[i + 2];
    const float v0 = __int_as_float(e0.y), v1 = __int_as_float(e1.y);
    const __half* b0 = h12 + (size_t)e0.x * 256 + c4;
    const __half* b1 = h12 + (size_t)e1.x * 256 + c4;
    const float4 g0p = gather8B(b0);
    const float4 g0q = gather8B(b0 + 128);
    const float4 g1p = gather8B(b1);
    const float4 g1q = gather8B(b1 + 128);
    fma4(p0, v0, g0p); fma4(q0, v0, g0q);
    fma4(p1, v1, g1p); fma4(q1, v1, g1q);
  }
  if (i < e) {
    const int2 e0 = ep[i];
    const float v0 = __int_as_float(e0.y);
    const __half* b0 = h12 + (size_t)e0.x * 256 + c4;
    fma4(p0, v0, gather8B(b0));
    fma4(q0, v0, gather8B(b0 + 128));
  }
  p0.x += p1.x; p0.y += p1.y; p0.z += p1.z; p0.w += p1.w;
  q0.x += q1.x; q0.y += q1.y; q0.z += q1.z; q0.w += q1.w;
  red4(p0);
  red4(q0);
  if (half == 0) {
    *reinterpret_cast<float4*>(out + (size_t)r * 384 + C + c4) = p0;
  } else {
    const __half2 qa = __float22half2_rn(make_float2(q0.x, q0.y));
    const __half2 qb = __float22half2_rn(make_float2(q0.z, q0.w));
    uint2 st;
    st.x = *reinterpret_cast<const unsigned*>(&qa);
    st.y = *reinterpret_cast<const unsigned*>(&qb);
    *reinterpret_cast<uint2*>(t + (size_t)r * tstride + c4) = st;
  }
}

// ---- SpMM: fp16 gather (stride hstride) -> fp32 out slice -------------
__global__ __launch_bounds__(256) void spmm_h2f(
    const __half* __restrict__ h, int hstride, const int* __restrict__ rp,
    const int2* __restrict__ ep, float* __restrict__ outp, int N, int ostride) {
  const int r = blockIdx.x * 4 + (threadIdx.x >> 6);
  if (r >= N) return;
  const int lane = threadIdx.x & 63;
  const int half = lane >> 5;
  const int c4 = (lane & 31) << 2;
  const int s = rp[r], e = rp[r + 1];
  float4 a0 = make_float4(0.f, 0.f, 0.f, 0.f), a1 = a0;
  int i = s + half;
  for (; i + 2 < e; i += 4) {
    const int2 e0 = ep[i], e1 = ep[i + 2];
    const float v0 = __int_as_float(e0.y), v1 = __int_as_float(e1.y);
    const float4 g0 = gather8B(h + (size_t)e0.x * hstride + c4);
    const float4 g1 = gather8B(h + (size_t)e1.x * hstride + c4);
    fma4(a0, v0, g0);
    fma4(a1, v1, g1);
  }
  if (i < e) {
    const int2 e0 = ep[i];
    fma4(a0, __int_as_float(e0.y), gather8B(h + (size_t)e0.x * hstride + c4));
  }
  a0.x += a1.x; a0.y += a1.y; a0.z += a1.z; a0.w += a1.w;
  red4(a0);
  if (half == 0)
    *reinterpret_cast<float4*>(outp + (size_t)r * ostride + c4) = a0;
}

// ---- SpMM: fp16 gather -> fp16 table (fallback path only) -------------
__global__ __launch_bounds__(256) void spmm_h2h(
    const __half* __restrict__ h, int hstride, const int* __restrict__ rp,
    const int2* __restrict__ ep, __half* __restrict__ outp, int ostride, int N) {
  const int r = blockIdx.x * 4 + (threadIdx.x >> 6);
  if (r >= N) return;
  const int lane = threadIdx.x & 63;
  const int half = lane >> 5;
  const int c4 = (lane & 31) << 2;
  const int s = rp[r], e = rp[r + 1];
  float4 a0 = make_float4(0.f, 0.f, 0.f, 0.f), a1 = a0;
  int i = s + half;
  for (; i + 2 < e; i += 4) {
    const int2 e0 = ep[i], e1 = ep[i + 2];
    fma4(a0, __int_as_float(e0.y), gather8B(h + (size_t)e0.x * hstride + c4));
    fma4(a1, __int_as_float(e1.y), gather8B(h + (size_t)e1.x * hstride + c4));
  }
  if (i < e) {
    const int2 e0 = ep[i];
    fma4(a0, __int_as_float(e0.y), gather8B(h + (size_t)e0.x * hstride + c4));
  }
  a0.x += a1.x; a0.y += a1.y; a0.z += a1.z; a0.w += a1.w;
  red4(a0);
  if (half == 0) {
    const __half2 qa = __float22half2_rn(make_float2(a0.x, a0.y));
    const __half2 qb = __float22half2_rn(make_float2(a0.z, a0.w));
    uint2 st;
    st.x = *reinterpret_cast<const unsigned*>(&qa);
    st.y = *reinterpret_cast<const unsigned*>(&qb);
    *reinterpret_cast<uint2*>(outp + (size_t)r * ostride + c4) = st;
  }
}

extern "C" void kernel_launch(void* const* d_in, const int* in_sizes, int n_in,
                              void* d_out, int out_size, void* d_ws, size_t ws_size,
                              hipStream_t stream) {
  const float* x  = (const float*)d_in[0];
  const float* W  = (const float*)d_in[1];
  const float* b  = (const float*)d_in[2];
  const float* ev = (const float*)d_in[3];
  const int*   er = (const int*)d_in[4];
  const int*   ec = (const int*)d_in[5];
  const int N = in_sizes[0] / C;
  const int E = in_sizes[3];
  float* out = (float*)d_out;

  // rows padded to 4096 -> chunks of 128 rows, count divisible by 8
  const int NP3 = ((N + 4095) / 4096) * 4096;
  const int nchunk = NP3 / 128;

  char* base = (char*)d_ws;
  size_t off = 0;
  auto alloc = [&](size_t bytes) {
    char* p = base + off;
    off += (bytes + 255) & ~(size_t)255;
    return p;
  };
  __half* h12 = (__half*)alloc((size_t)N * 256 * 2);  // interleaved h1|h2
  unsigned short* xh = (unsigned short*)alloc((size_t)NP3 * C * 2);
  unsigned short* xl = (unsigned short*)alloc((size_t)NP3 * C * 2);
  unsigned short* wf = (unsigned short*)alloc((size_t)12 * 8192 * 2);
  int* row_ptr = (int*)alloc((size_t)(N + 1) * 4);
  int* cursor  = (int*)alloc((size_t)N * 4);
  int* bsum    = (int*)alloc(64 * 4);
  int2* ep     = (int2*)alloc((size_t)E * 8);
  const size_t need_t = off + (size_t)N * C * 2;
  __half* t;
  int tstride;
  bool merged;
  if (ws_size >= need_t) {
    t = (__half*)alloc((size_t)N * C * 2);
    tstride = C;
    merged = true;
  } else {
    t = h12;        // alias h1-slots (dead after pass-1), stride 256
    tstride = 256;
    merged = false;
  }

  const int nb = (N + 1023) / 1024;

  // fused prep: W planes + x split + cursor zeroing (one dispatch)
  prep_fused<<<(NP3 * C + 255) / 256, 256, 0, stream>>>(W, wf, x, xh, xl,
                                                        cursor, N, NP3);

  // CSR build
  const int eb0 = (E + 255) / 256;
  const int eblocks = eb0 < 2048 ? eb0 : 2048;
  hist_rows<<<eblocks, 256, 0, stream>>>(er, cursor, E);
  scan_local<<<nb, 1024, 0, stream>>>(cursor, row_ptr, bsum, N);
  scan_apply2<<<nb, 1024, 0, stream>>>(row_ptr, bsum, cursor, row_ptr, nb, N);
  scatter_edges<<<eblocks, 256, 0, stream>>>(er, ec, ev, cursor, ep, E);

  // fused linears (MFMA, W-stationary in VGPRs, 128-row chunks, 4 blk/CU)
  gemm3_ws<<<6 * nchunk, 256, 0, stream>>>(xh, xl, wf, b, out, h12, N);

  // SpMM passes
  const int sblocks = (N + 3) / 4;
  if (merged) {
    spmm12<<<sblocks, 256, 0, stream>>>(h12, row_ptr, ep, out, t, tstride, N);
  } else {
    spmm_h2f<<<sblocks, 256, 0, stream>>>(h12, 256, row_ptr, ep, out + C, N, 3 * C);
    spmm_h2h<<<sblocks, 256, 0, stream>>>(h12 + 128, 256, row_ptr, ep, t, tstride, N);
  }
  spmm_h2f<<<sblocks, 256, 0, stream>>>(t, tstride, row_ptr, ep, out + 2 * C, N, 3 * C);
}

// Round 15
// 200.767 us; speedup vs baseline: 1.1903x; 1.1903x over previous
//
#include <hip/hip_runtime.h>
#include <hip/hip_fp16.h>
#include <cstddef>
#include <cstdint>

#define C 128

typedef short bf16x8 __attribute__((ext_vector_type(8)));
typedef float f32x4 __attribute__((ext_vector_type(4)));

__device__ __forceinline__ unsigned f2bf_hi(float f) {
  unsigned u = __float_as_uint(f);
  return (u + 0x7fffu + ((u >> 16) & 1u)) >> 16;
}

__device__ __forceinline__ float4 gather8B(const __half* p) {
  const uint2 u = *reinterpret_cast<const uint2*>(p);
  const __half2 a = *reinterpret_cast<const __half2*>(&u.x);
  const __half2 b = *reinterpret_cast<const __half2*>(&u.y);
  const float2 lo = __half22float2(a), hi = __half22float2(b);
  return make_float4(lo.x, lo.y, hi.x, hi.y);
}

__device__ __forceinline__ void fma4(float4& acc, float v, const float4& g) {
  acc.x += v * g.x; acc.y += v * g.y; acc.z += v * g.z; acc.w += v * g.w;
}

__device__ __forceinline__ void red4(float4& a) {
  a.x += __shfl_xor(a.x, 32);
  a.y += __shfl_xor(a.y, 32);
  a.z += __shfl_xor(a.z, 32);
  a.w += __shfl_xor(a.w, 32);
}

// ---- fused prep: W planes + x hi/lo split + cursor zeroing ------------
// W layout (verified R8): 12 planes (j*4 + half*2 + ch), 8192 shorts each;
// off = kc*2048 + ct*512 + (g*16+l15)*8 + i.
__global__ __launch_bounds__(256) void prep_fused(
    const float* __restrict__ W, unsigned short* __restrict__ wf,
    const float* __restrict__ x, unsigned short* __restrict__ xh,
    unsigned short* __restrict__ xl, int* __restrict__ cursor,
    int N, int NP) {
  const int idx = blockIdx.x * 256 + threadIdx.x;
  if (idx < NP * C) {
    const float v = (idx < N * C) ? x[idx] : 0.0f;
    const unsigned hb = f2bf_hi(v);
    const unsigned lb = f2bf_hi(v - __uint_as_float(hb << 16));
    xh[idx] = (unsigned short)hb;
    xl[idx] = (unsigned short)lb;
  }
  if (idx < 3 * 128 * 128) {
    const int j = idx >> 14, k = (idx >> 7) & 127, c = idx & 127;
    const float v = W[idx];
    const unsigned hb = f2bf_hi(v);
    const unsigned lb = f2bf_hi(v - __uint_as_float(hb << 16));
    const int ch = c >> 6, cc = c & 63, ct = cc >> 4, l15 = cc & 15;
    const int kc = k >> 5, kk = k & 31, g = kk >> 3, i = kk & 7;
    const int off = kc * 2048 + ct * 512 + (g * 16 + l15) * 8 + i;
    wf[(size_t)(j * 4 + 0 + ch) * 8192 + off] = (unsigned short)hb;
    wf[(size_t)(j * 4 + 2 + ch) * 8192 + off] = (unsigned short)lb;
  }
  if (idx < N) cursor[idx] = 0;
}

// ---- fused 3x linear: W-stationary in VGPRs, stream x rows ------------
// R12 configuration (best measured): chunk = 512 rows, 8 tiles per wave,
// 2-deep A prefetch, launch_bounds (256,2) so the 128 B-frag VGPRs stay
// register-resident (NEVER raise min-waves: R14 showed it forces B-refetch,
// FETCH 15.7 -> 107 MB, 47 -> 82 us).
// bid -> (chunk, v): chunk = (bid%8) + 8*(bid/48), v = (bid%48)>>3 = j*2+ch.
// h1/h2 interleaved into h12 [N][256]: j==1 at +0, j==2 at +128.
__global__ __launch_bounds__(256, 2) void gemm3_ws(
    const unsigned short* __restrict__ xh, const unsigned short* __restrict__ xl,
    const unsigned short* __restrict__ wf, const float* __restrict__ bias,
    float* __restrict__ out, __half* __restrict__ h12, int N) {
  const int bid = blockIdx.x;
  const int q48 = bid / 48, r48 = bid % 48;
  const int chunk = (r48 & 7) + 8 * q48;
  const int v = r48 >> 3;  // 0..5
  const int j = v >> 1, ch = v & 1;
  const int tid = threadIdx.x;
  const int lane = tid & 63, wid = tid >> 6;
  const int l15 = lane & 15, g = lane >> 4;

  // stationary B fragments (128 VGPRs)
  const unsigned short* ph = wf + (size_t)(j * 4 + 0 + ch) * 8192 + lane * 8;
  const unsigned short* pl = wf + (size_t)(j * 4 + 2 + ch) * 8192 + lane * 8;
  bf16x8 bh[4][4], bl[4][4];
#pragma unroll
  for (int kc = 0; kc < 4; ++kc)
#pragma unroll
    for (int ct = 0; ct < 4; ++ct) {
      bh[kc][ct] = *reinterpret_cast<const bf16x8*>(ph + kc * 2048 + ct * 512);
      bl[kc][ct] = *reinterpret_cast<const bf16x8*>(pl + kc * 2048 + ct * 512);
    }

  float bv[4];
#pragma unroll
  for (int ct = 0; ct < 4; ++ct) bv[ct] = bias[j * C + ch * 64 + ct * 16 + l15];

  const int t0 = chunk * 32 + wid;  // 16-row tile id, step 4 per wave

  bf16x8 a0h[4], a0l[4], a1h[4], a1l[4];

#define LOADA(AH, AL, T)                                                    \
  {                                                                         \
    const size_t ar = (size_t)((T)*16 + l15) * C + g * 8;                   \
    _Pragma("unroll") for (int kc = 0; kc < 4; ++kc) {                      \
      AH[kc] = *reinterpret_cast<const bf16x8*>(xh + ar + kc * 32);         \
      AL[kc] = *reinterpret_cast<const bf16x8*>(xl + ar + kc * 32);         \
    }                                                                       \
  }

#define COMPSTORE(AH, AL, T)                                                \
  {                                                                         \
    f32x4 acc[4];                                                           \
    _Pragma("unroll") for (int ct = 0; ct < 4; ++ct)                        \
        acc[ct] = (f32x4){0.f, 0.f, 0.f, 0.f};                              \
    _Pragma("unroll") for (int kc = 0; kc < 4; ++kc)                        \
        _Pragma("unroll") for (int ct = 0; ct < 4; ++ct) {                  \
      acc[ct] = __builtin_amdgcn_mfma_f32_16x16x32_bf16(AH[kc], bh[kc][ct], \
                                                        acc[ct], 0, 0, 0);  \
      acc[ct] = __builtin_amdgcn_mfma_f32_16x16x32_bf16(AL[kc], bh[kc][ct], \
                                                        acc[ct], 0, 0, 0);  \
      acc[ct] = __builtin_amdgcn_mfma_f32_16x16x32_bf16(AH[kc], bl[kc][ct], \
                                                        acc[ct], 0, 0, 0);  \
    }                                                                       \
    const int grb = (T)*16 + g * 4;                                         \
    if (j == 0) {                                                           \
      _Pragma("unroll") for (int ct = 0; ct < 4; ++ct) {                    \
        const int col = ch * 64 + ct * 16 + l15;                            \
        _Pragma("unroll") for (int qq = 0; qq < 4; ++qq) {                  \
          const int gr = grb + qq;                                          \
          if (gr < N) out[(size_t)gr * 384 + col] = acc[ct][qq] + bv[ct];   \
        }                                                                   \
      }                                                                     \
    } else {                                                                \
      __half* const hp = h12 + ((j == 2) ? 128 : 0);                        \
      _Pragma("unroll") for (int ct = 0; ct < 4; ++ct) {                    \
        const int colb = ch * 64 + ct * 16 + (l15 & ~1);                    \
        _Pragma("unroll") for (int qq = 0; qq < 4; ++qq) {                  \
          const int gr = grb + qq;                                          \
          const float fv = acc[ct][qq] + bv[ct];                            \
          const unsigned mine = (unsigned)__half_as_ushort(__float2half(fv));\
          const unsigned nbr = (unsigned)__shfl_xor((int)mine, 1);          \
          if (((l15 & 1) == 0) && gr < N) {                                 \
            *reinterpret_cast<unsigned*>(hp + (size_t)gr * 256 + colb) =    \
                mine | (nbr << 16);                                         \
          }                                                                 \
        }                                                                   \
      }                                                                     \
    }                                                                       \
  }

  LOADA(a0h, a0l, t0);
#pragma unroll
  for (int ti = 0; ti < 8; ti += 2) {
    LOADA(a1h, a1l, t0 + (ti + 1) * 4);
    COMPSTORE(a0h, a0l, t0 + ti * 4);
    if (ti + 2 < 8) LOADA(a0h, a0l, t0 + (ti + 2) * 4);
    COMPSTORE(a1h, a1l, t0 + (ti + 1) * 4);
  }
#undef LOADA
#undef COMPSTORE
}

// ---- CSR build --------------------------------------------------------
__global__ __launch_bounds__(256) void hist_rows(
    const int* __restrict__ row, int* __restrict__ cnt, int E) {
  int i = blockIdx.x * 256 + threadIdx.x;
  int stride = gridDim.x * 256;
  for (; i < E; i += stride) atomicAdd(&cnt[row[i]], 1);
}

__global__ __launch_bounds__(1024) void scan_local(
    const int* __restrict__ cnt, int* __restrict__ part,
    int* __restrict__ bsum, int N) {
  __shared__ int wsum[16];
  const int tid = threadIdx.x;
  const int i = blockIdx.x * 1024 + tid;
  const int v = (i < N) ? cnt[i] : 0;
  const int lane = tid & 63, w = tid >> 6;
  int s = v;
#pragma unroll
  for (int off = 1; off < 64; off <<= 1) {
    int t = __shfl_up(s, off, 64);
    if (lane >= off) s += t;
  }
  if (lane == 63) wsum[w] = s;
  __syncthreads();
  if (tid < 16) {
    int ws = wsum[tid];
#pragma unroll
    for (int off = 1; off < 16; off <<= 1) {
      int t = __shfl_up(ws, off, 16);
      if (tid >= off) ws += t;
    }
    wsum[tid] = ws;
  }
  __syncthreads();
  const int woff = w ? wsum[w - 1] : 0;
  if (i < N) part[i] = woff + s - v;
  if (tid == 0) bsum[blockIdx.x] = wsum[15];
}

// apply: part[i] += carry(bid); cursor = part; block0 writes row_ptr[N].
__global__ __launch_bounds__(1024) void scan_apply2(
    int* __restrict__ part, const int* __restrict__ bsum,
    int* __restrict__ cursor, int* __restrict__ row_ptr, int nb, int N) {
  __shared__ int carry_s;
  const int tid = threadIdx.x;
  if (tid < 64) {
    const int v = (tid < nb) ? bsum[tid] : 0;
    int s = v;
#pragma unroll
    for (int off = 1; off < 64; off <<= 1) {
      int t = __shfl_up(s, off, 64);
      if (tid >= off) s += t;
    }
    if (tid == (int)blockIdx.x) carry_s = s - v;
    if (blockIdx.x == 0 && tid == 63) row_ptr[N] = s;
  }
  __syncthreads();
  const int i = blockIdx.x * 1024 + tid;
  if (i < N) {
    const int v = part[i] + carry_s;
    part[i] = v;
    cursor[i] = v;
  }
}

__global__ __launch_bounds__(256) void scatter_edges(
    const int* __restrict__ row, const int* __restrict__ col,
    const float* __restrict__ val, int* __restrict__ cursor,
    int2* __restrict__ ep, int E) {
  int i = blockIdx.x * 256 + threadIdx.x;
  int stride = gridDim.x * 256;
  for (; i < E; i += stride) {
    int r = row[i];
    int pos = atomicAdd(&cursor[r], 1);
    ep[pos] = make_int2(col[i], __float_as_int(val[i]));
  }
}

// ---- SpMM merged: out[:,128:256] = A h1 ; t = A h2 --------------------
__global__ __launch_bounds__(256) void spmm12(
    const __half* __restrict__ h12, const int* __restrict__ rp,
    const int2* __restrict__ ep, float* __restrict__ out,
    __half* __restrict__ t, int tstride, int N) {
  const int r = blockIdx.x * 4 + (threadIdx.x >> 6);
  if (r >= N) return;
  const int lane = threadIdx.x & 63;
  const int half = lane >> 5;
  const int c4 = (lane & 31) << 2;
  const int s = rp[r], e = rp[r + 1];
  float4 p0 = make_float4(0.f, 0.f, 0.f, 0.f), p1 = p0, q0 = p0, q1 = p0;
  int i = s + half;
  for (; i + 2 < e; i += 4) {
    const int2 e0 = ep[i], e1 = ep[i + 2];
    const float v0 = __int_as_float(e0.y), v1 = __int_as_float(e1.y);
    const __half* b0 = h12 + (size_t)e0.x * 256 + c4;
    const __half* b1 = h12 + (size_t)e1.x * 256 + c4;
    const float4 g0p = gather8B(b0);
    const float4 g0q = gather8B(b0 + 128);
    const float4 g1p = gather8B(b1);
    const float4 g1q = gather8B(b1 + 128);
    fma4(p0, v0, g0p); fma4(q0, v0, g0q);
    fma4(p1, v1, g1p); fma4(q1, v1, g1q);
  }
  if (i < e) {
    const int2 e0 = ep[i];
    const float v0 = __int_as_float(e0.y);
    const __half* b0 = h12 + (size_t)e0.x * 256 + c4;
    fma4(p0, v0, gather8B(b0));
    fma4(q0, v0, gather8B(b0 + 128));
  }
  p0.x += p1.x; p0.y += p1.y; p0.z += p1.z; p0.w += p1.w;
  q0.x += q1.x; q0.y += q1.y; q0.z += q1.z; q0.w += q1.w;
  red4(p0);
  red4(q0);
  if (half == 0) {
    *reinterpret_cast<float4*>(out + (size_t)r * 384 + C + c4) = p0;
  } else {
    const __half2 qa = __float22half2_rn(make_float2(q0.x, q0.y));
    const __half2 qb = __float22half2_rn(make_float2(q0.z, q0.w));
    uint2 st;
    st.x = *reinterpret_cast<const unsigned*>(&qa);
    st.y = *reinterpret_cast<const unsigned*>(&qb);
    *reinterpret_cast<uint2*>(t + (size_t)r * tstride + c4) = st;
  }
}

// ---- SpMM: fp16 gather (stride hstride) -> fp32 out slice -------------
__global__ __launch_bounds__(256) void spmm_h2f(
    const __half* __restrict__ h, int hstride, const int* __restrict__ rp,
    const int2* __restrict__ ep, float* __restrict__ outp, int N, int ostride) {
  const int r = blockIdx.x * 4 + (threadIdx.x >> 6);
  if (r >= N) return;
  const int lane = threadIdx.x & 63;
  const int half = lane >> 5;
  const int c4 = (lane & 31) << 2;
  const int s = rp[r], e = rp[r + 1];
  float4 a0 = make_float4(0.f, 0.f, 0.f, 0.f), a1 = a0;
  int i = s + half;
  for (; i + 2 < e; i += 4) {
    const int2 e0 = ep[i], e1 = ep[i + 2];
    const float v0 = __int_as_float(e0.y), v1 = __int_as_float(e1.y);
    const float4 g0 = gather8B(h + (size_t)e0.x * hstride + c4);
    const float4 g1 = gather8B(h + (size_t)e1.x * hstride + c4);
    fma4(a0, v0, g0);
    fma4(a1, v1, g1);
  }
  if (i < e) {
    const int2 e0 = ep[i];
    fma4(a0, __int_as_float(e0.y), gather8B(h + (size_t)e0.x * hstride + c4));
  }
  a0.x += a1.x; a0.y += a1.y; a0.z += a1.z; a0.w += a1.w;
  red4(a0);
  if (half == 0)
    *reinterpret_cast<float4*>(outp + (size_t)r * ostride + c4) = a0;
}

// ---- SpMM: fp16 gather -> fp16 table (fallback path only) -------------
__global__ __launch_bounds__(256) void spmm_h2h(
    const __half* __restrict__ h, int hstride, const int* __restrict__ rp,
    const int2* __restrict__ ep, __half* __restrict__ outp, int ostride, int N) {
  const int r = blockIdx.x * 4 + (threadIdx.x >> 6);
  if (r >= N) return;
  const int lane = threadIdx.x & 63;
  const int half = lane >> 5;
  const int c4 = (lane & 31) << 2;
  const int s = rp[r], e = rp[r + 1];
  float4 a0 = make_float4(0.f, 0.f, 0.f, 0.f), a1 = a0;
  int i = s + half;
  for (; i + 2 < e; i += 4) {
    const int2 e0 = ep[i], e1 = ep[i + 2];
    fma4(a0, __int_as_float(e0.y), gather8B(h + (size_t)e0.x * hstride + c4));
    fma4(a1, __int_as_float(e1.y), gather8B(h + (size_t)e1.x * hstride + c4));
  }
  if (i < e) {
    const int2 e0 = ep[i];
    fma4(a0, __int_as_float(e0.y), gather8B(h + (size_t)e0.x * hstride + c4));
  }
  a0.x += a1.x; a0.y += a1.y; a0.z += a1.z; a0.w += a1.w;
  red4(a0);
  if (half == 0) {
    const __half2 qa = __float22half2_rn(make_float2(a0.x, a0.y));
    const __half2 qb = __float22half2_rn(make_float2(a0.z, a0.w));
    uint2 st;
    st.x = *reinterpret_cast<const unsigned*>(&qa);
    st.y = *reinterpret_cast<const unsigned*>(&qb);
    *reinterpret_cast<uint2*>(outp + (size_t)r * ostride + c4) = st;
  }
}

extern "C" void kernel_launch(void* const* d_in, const int* in_sizes, int n_in,
                              void* d_out, int out_size, void* d_ws, size_t ws_size,
                              hipStream_t stream) {
  const float* x  = (const float*)d_in[0];
  const float* W  = (const float*)d_in[1];
  const float* b  = (const float*)d_in[2];
  const float* ev = (const float*)d_in[3];
  const int*   er = (const int*)d_in[4];
  const int*   ec = (const int*)d_in[5];
  const int N = in_sizes[0] / C;
  const int E = in_sizes[3];
  float* out = (float*)d_out;

  // rows padded to 4096 (512 rows/chunk x 8 chunks per XCD-group)
  const int NP3 = ((N + 4095) / 4096) * 4096;
  const int nchunk = NP3 / 512;

  char* base = (char*)d_ws;
  size_t off = 0;
  auto alloc = [&](size_t bytes) {
    char* p = base + off;
    off += (bytes + 255) & ~(size_t)255;
    return p;
  };
  __half* h12 = (__half*)alloc((size_t)N * 256 * 2);  // interleaved h1|h2
  unsigned short* xh = (unsigned short*)alloc((size_t)NP3 * C * 2);
  unsigned short* xl = (unsigned short*)alloc((size_t)NP3 * C * 2);
  unsigned short* wf = (unsigned short*)alloc((size_t)12 * 8192 * 2);
  int* row_ptr = (int*)alloc((size_t)(N + 1) * 4);
  int* cursor  = (int*)alloc((size_t)N * 4);
  int* bsum    = (int*)alloc(64 * 4);
  int2* ep     = (int2*)alloc((size_t)E * 8);
  const size_t need_t = off + (size_t)N * C * 2;
  __half* t;
  int tstride;
  bool merged;
  if (ws_size >= need_t) {
    t = (__half*)alloc((size_t)N * C * 2);
    tstride = C;
    merged = true;
  } else {
    t = h12;        // alias h1-slots (dead after pass-1), stride 256
    tstride = 256;
    merged = false;
  }

  const int nb = (N + 1023) / 1024;

  // fused prep: W planes + x split + cursor zeroing (one dispatch)
  prep_fused<<<(NP3 * C + 255) / 256, 256, 0, stream>>>(W, wf, x, xh, xl,
                                                        cursor, N, NP3);

  // CSR build
  const int eb0 = (E + 255) / 256;
  const int eblocks = eb0 < 2048 ? eb0 : 2048;
  hist_rows<<<eblocks, 256, 0, stream>>>(er, cursor, E);
  scan_local<<<nb, 1024, 0, stream>>>(cursor, row_ptr, bsum, N);
  scan_apply2<<<nb, 1024, 0, stream>>>(row_ptr, bsum, cursor, row_ptr, nb, N);
  scatter_edges<<<eblocks, 256, 0, stream>>>(er, ec, ev, cursor, ep, E);

  // fused linears (MFMA, W-stationary in VGPRs, 512-row chunks, 2 blk/CU)
  gemm3_ws<<<6 * nchunk, 256, 0, stream>>>(xh, xl, wf, b, out, h12, N);

  // SpMM passes
  const int sblocks = (N + 3) / 4;
  if (merged) {
    spmm12<<<sblocks, 256, 0, stream>>>(h12, row_ptr, ep, out, t, tstride, N);
  } else {
    spmm_h2f<<<sblocks, 256, 0, stream>>>(h12, 256, row_ptr, ep, out + C, N, 3 * C);
    spmm_h2h<<<sblocks, 256, 0, stream>>>(h12 + 128, 256, row_ptr, ep, t, tstride, N);
  }
  spmm_h2f<<<sblocks, 256, 0, stream>>>(t, tstride, row_ptr, ep, out + 2 * C, N, 3 * C);
}